// Round 10
// baseline (25.565 us; speedup 1.0000x reference)
//
#include <hip/hip_runtime.h>

// CustomBatchNorm2D forward — single pass over x, 2 channels per block,
// overlapped R/W streams + counted-vmcnt staircase reduction.
//
// x (N=32, C=512, H=32, W=32) f32.
//   S[i,c]  = sum_hw x[i,c,:]
//   mean[c] = sum_i S[i,c] / (N*HW)
//   diag[c] = sum_i (S[i,c] - HW*mean[c])^2 / HW
//   out     = A[c]*x + B[c],  A = gamma[c]*abs(diag[c]),  B = beta[c] - A*mean[c]
//
// Round-9 post-mortem: the pin-all placed BEFORE each reduce forced a full
// vmcnt drain of that channel's loads before the first add; reduction (and
// the dependent stats/stores) started at last-load-landed instead of
// streaming. This version:
//   * all 16 loads issued at the top (sched_barrier keeps the cluster),
//   * reduce loops read d[k] directly -> compiler emits a counted vmcnt
//     staircase (consume each load as it lands),
//   * the anti-rematerialization pin moves to AFTER each reduce (free:
//     waits already satisfied; still blocks re-loading for the stores),
//   * LDS-only barriers (lgkmcnt + s_barrier, no vmcnt drain),
//   * nontemporal loads/stores (pure streaming, zero reuse).
//
// Grid: 256 blocks x 1024 threads = 1 block/CU. Thread map: row r = t>>5
// (32 lanes per row), float4 slots j + 32k, k=0..7.

#define HW_   1024
#define C_    512
#define N_    32

typedef float f4 __attribute__((ext_vector_type(4)));

__global__ void __launch_bounds__(1024)
bn_pipe4(const float* __restrict__ x,
         const float* __restrict__ gamma,
         const float* __restrict__ beta,
         float* __restrict__ out) {
    const int t  = threadIdx.x;
    const int r  = t >> 5;          // sample/row 0..31
    const int j  = t & 31;          // float4 slot base within row
    const int c0 = blockIdx.x;
    const int c1 = c0 + 256;

    const f4* xv = reinterpret_cast<const f4*>(x);
    f4*       ov = reinterpret_cast<f4*>(out);
    const size_t base0 = (((size_t)(r * C_ + c0)) << 8) + j;
    const size_t base1 = (((size_t)(r * C_ + c1)) << 8) + j;

    __shared__ float Sl0[N_], Sl1[N_];

    // ---- issue ALL loads up front: continuous chip-wide read stream ----
    f4 d0[8], d1[8];
    #pragma unroll
    for (int k = 0; k < 8; ++k)
        d0[k] = __builtin_nontemporal_load(xv + base0 + k * 32);
    #pragma unroll
    for (int k = 0; k < 8; ++k)
        d1[k] = __builtin_nontemporal_load(xv + base1 + k * 32);
    __builtin_amdgcn_sched_barrier(0);   // keep the 16-load cluster here

    // ---- reduce c0 directly from d0: counted-vmcnt staircase ----
    {
        float s = 0.f;
        #pragma unroll
        for (int k = 0; k < 8; ++k)
            s += (d0[k].x + d0[k].y) + (d0[k].z + d0[k].w);
        #pragma unroll
        for (int off = 16; off > 0; off >>= 1)
            s += __shfl_xor(s, off, 64);     // stays within the 32-lane group
        if (j == 0) Sl0[r] = s;
    }
    // pin AFTER reduce: waits already satisfied; blocks rematerialization
    #pragma unroll
    for (int k = 0; k < 8; ++k)
        asm volatile("" : "+v"(d0[k]));

    // ---- LDS-only barrier: does NOT drain vmcnt (d1 stays in flight) ----
    asm volatile("s_waitcnt lgkmcnt(0)" ::: "memory");
    __builtin_amdgcn_s_barrier();

    // ---- stats c0 (redundant per thread; uniform LDS broadcasts) ----
    float A0, B0;
    {
        float tot = 0.f;
        #pragma unroll
        for (int i = 0; i < N_; ++i) tot += Sl0[i];
        const float mean  = tot * (1.0f / (float)(N_ * HW_));
        const float m1024 = tot * (1.0f / (float)N_);
        float dd = 0.f;
        #pragma unroll
        for (int i = 0; i < N_; ++i) {
            const float e = Sl0[i] - m1024;
            dd += e * e;
        }
        const float diag = dd * (1.0f / (float)HW_);
        A0 = gamma[c0] * fabsf(diag);
        B0 = beta[c0] - A0 * mean;
    }

    // ---- store c0 (c1 reads still streaming underneath) ----
    #pragma unroll
    for (int k = 0; k < 8; ++k) {
        f4 o;
        o.x = fmaf(A0, d0[k].x, B0);
        o.y = fmaf(A0, d0[k].y, B0);
        o.z = fmaf(A0, d0[k].z, B0);
        o.w = fmaf(A0, d0[k].w, B0);
        __builtin_nontemporal_store(o, ov + base0 + k * 32);
    }

    // ---- reduce c1 directly from d1: staircase (mostly landed by now) ----
    {
        float s = 0.f;
        #pragma unroll
        for (int k = 0; k < 8; ++k)
            s += (d1[k].x + d1[k].y) + (d1[k].z + d1[k].w);
        #pragma unroll
        for (int off = 16; off > 0; off >>= 1)
            s += __shfl_xor(s, off, 64);
        if (j == 0) Sl1[r] = s;
    }
    #pragma unroll
    for (int k = 0; k < 8; ++k)
        asm volatile("" : "+v"(d1[k]));

    asm volatile("s_waitcnt lgkmcnt(0)" ::: "memory");
    __builtin_amdgcn_s_barrier();

    // ---- stats c1 ----
    float A1, B1;
    {
        float tot = 0.f;
        #pragma unroll
        for (int i = 0; i < N_; ++i) tot += Sl1[i];
        const float mean  = tot * (1.0f / (float)(N_ * HW_));
        const float m1024 = tot * (1.0f / (float)N_);
        float dd = 0.f;
        #pragma unroll
        for (int i = 0; i < N_; ++i) {
            const float e = Sl1[i] - m1024;
            dd += e * e;
        }
        const float diag = dd * (1.0f / (float)HW_);
        A1 = gamma[c1] * fabsf(diag);
        B1 = beta[c1] - A1 * mean;
    }

    // ---- store c1 (exposed tail: pure writes, nothing left to overlap) ----
    #pragma unroll
    for (int k = 0; k < 8; ++k) {
        f4 o;
        o.x = fmaf(A1, d1[k].x, B1);
        o.y = fmaf(A1, d1[k].y, B1);
        o.z = fmaf(A1, d1[k].z, B1);
        o.w = fmaf(A1, d1[k].w, B1);
        __builtin_nontemporal_store(o, ov + base1 + k * 32);
    }
}

extern "C" void kernel_launch(void* const* d_in, const int* in_sizes, int n_in,
                              void* d_out, int out_size, void* d_ws, size_t ws_size,
                              hipStream_t stream) {
    const float* x     = (const float*)d_in[0];
    const float* gamma = (const float*)d_in[1];
    const float* beta  = (const float*)d_in[2];
    float*       out   = (float*)d_out;

    bn_pipe4<<<256, 1024, 0, stream>>>(x, gamma, beta, out);
    (void)in_sizes; (void)n_in; (void)out_size; (void)d_ws; (void)ws_size;
}

// Round 11
// 25.075 us; speedup vs baseline: 1.0195x; 1.0195x over previous
//
#include <hip/hip_runtime.h>

// CustomBatchNorm2D forward — single pass, minimal-bubble SERIAL schedule:
//   [read 64 MiB pure] -> one LDS barrier -> [write 64 MiB pure].
//
// x (N=32, C=512, H=32, W=32) f32.
//   S[i,c]  = sum_hw x[i,c,:]
//   mean[c] = sum_i S[i,c] / (N*HW)
//   diag[c] = sum_i (S[i,c] - HW*mean[c])^2 / HW
//   out     = A[c]*x + B[c],  A = gamma[c]*abs(diag[c]),  B = beta[c] - A*mean[c]
//
// Rationale (rounds 6-10 post-mortem): HBM mixed R/W streams run slower than
// pure streams (fills sustain ~6.9 TB/s pure). The overlapped pipelines
// (R9/R10) mixed the streams and plateaued at ~25 µs; the serial variants
// (R6-R8) paid two barrier+stats+drain rounds. This kernel is serial with
// exactly ONE barrier and ONE stats phase:
//   issue all 16 loads -> staircase-reduce c0 then c1 (consume as they land,
//   read stream never stalls) -> lgkmcnt-only barrier -> stats both ->
//   16 stores back-to-back.
//
// Grid: 256 blocks x 1024 threads = 1 block/CU. Thread map: row r = t>>5
// (32 lanes per row), float4 slots j + 32k, k=0..7. Channels c0=b, c1=b+256.

#define HW_   1024
#define C_    512
#define N_    32

typedef float f4 __attribute__((ext_vector_type(4)));

__global__ void __launch_bounds__(1024)
bn_serial(const float* __restrict__ x,
          const float* __restrict__ gamma,
          const float* __restrict__ beta,
          float* __restrict__ out) {
    const int t  = threadIdx.x;
    const int r  = t >> 5;          // sample/row 0..31
    const int j  = t & 31;          // float4 slot base within row
    const int c0 = blockIdx.x;
    const int c1 = c0 + 256;

    const f4* xv = reinterpret_cast<const f4*>(x);
    f4*       ov = reinterpret_cast<f4*>(out);
    const size_t base0 = (((size_t)(r * C_ + c0)) << 8) + j;
    const size_t base1 = (((size_t)(r * C_ + c1)) << 8) + j;

    __shared__ float Sl0[N_], Sl1[N_];

    // ---- issue ALL 16 loads: one continuous pure-read stream ----
    f4 d0[8], d1[8];
    #pragma unroll
    for (int k = 0; k < 8; ++k)
        d0[k] = __builtin_nontemporal_load(xv + base0 + k * 32);
    #pragma unroll
    for (int k = 0; k < 8; ++k)
        d1[k] = __builtin_nontemporal_load(xv + base1 + k * 32);
    __builtin_amdgcn_sched_barrier(0);   // keep the 16-load cluster here

    // ---- staircase reduce c0 (consume loads as they land) ----
    {
        float s = 0.f;
        #pragma unroll
        for (int k = 0; k < 8; ++k)
            s += (d0[k].x + d0[k].y) + (d0[k].z + d0[k].w);
        #pragma unroll
        for (int off = 16; off > 0; off >>= 1)
            s += __shfl_xor(s, off, 64);     // stays within the 32-lane group
        if (j == 0) Sl0[r] = s;
    }
    #pragma unroll
    for (int k = 0; k < 8; ++k)
        asm volatile("" : "+v"(d0[k]));      // block rematerialization

    // ---- staircase reduce c1 ----
    {
        float s = 0.f;
        #pragma unroll
        for (int k = 0; k < 8; ++k)
            s += (d1[k].x + d1[k].y) + (d1[k].z + d1[k].w);
        #pragma unroll
        for (int off = 16; off > 0; off >>= 1)
            s += __shfl_xor(s, off, 64);
        if (j == 0) Sl1[r] = s;
    }
    #pragma unroll
    for (int k = 0; k < 8; ++k)
        asm volatile("" : "+v"(d1[k]));

    // ---- the ONE barrier (LDS-only; vmcnt already drained by consumption) --
    asm volatile("s_waitcnt lgkmcnt(0)" ::: "memory");
    __builtin_amdgcn_s_barrier();

    // ---- stats for both channels (redundant per thread, LDS broadcasts) ----
    float A0, B0, A1, B1;
    {
        float tot0 = 0.f, tot1 = 0.f;
        #pragma unroll
        for (int i = 0; i < N_; ++i) { tot0 += Sl0[i]; tot1 += Sl1[i]; }
        const float mean0  = tot0 * (1.0f / (float)(N_ * HW_));
        const float mean1  = tot1 * (1.0f / (float)(N_ * HW_));
        const float m0     = tot0 * (1.0f / (float)N_);   // HW * mean
        const float m1     = tot1 * (1.0f / (float)N_);
        float dd0 = 0.f, dd1 = 0.f;
        #pragma unroll
        for (int i = 0; i < N_; ++i) {
            const float e0 = Sl0[i] - m0;
            const float e1 = Sl1[i] - m1;
            dd0 += e0 * e0;
            dd1 += e1 * e1;
        }
        A0 = gamma[c0] * fabsf(dd0 * (1.0f / (float)HW_));
        B0 = beta[c0] - A0 * mean0;
        A1 = gamma[c1] * fabsf(dd1 * (1.0f / (float)HW_));
        B1 = beta[c1] - A1 * mean1;
    }

    // ---- all 16 stores back-to-back: one continuous pure-write stream ----
    #pragma unroll
    for (int k = 0; k < 8; ++k) {
        f4 o;
        o.x = fmaf(A0, d0[k].x, B0);
        o.y = fmaf(A0, d0[k].y, B0);
        o.z = fmaf(A0, d0[k].z, B0);
        o.w = fmaf(A0, d0[k].w, B0);
        __builtin_nontemporal_store(o, ov + base0 + k * 32);
    }
    #pragma unroll
    for (int k = 0; k < 8; ++k) {
        f4 o;
        o.x = fmaf(A1, d1[k].x, B1);
        o.y = fmaf(A1, d1[k].y, B1);
        o.z = fmaf(A1, d1[k].z, B1);
        o.w = fmaf(A1, d1[k].w, B1);
        __builtin_nontemporal_store(o, ov + base1 + k * 32);
    }
}

extern "C" void kernel_launch(void* const* d_in, const int* in_sizes, int n_in,
                              void* d_out, int out_size, void* d_ws, size_t ws_size,
                              hipStream_t stream) {
    const float* x     = (const float*)d_in[0];
    const float* gamma = (const float*)d_in[1];
    const float* beta  = (const float*)d_in[2];
    float*       out   = (float*)d_out;

    bn_serial<<<256, 1024, 0, stream>>>(x, gamma, beta, out);
    (void)in_sizes; (void)n_in; (void)out_size; (void)d_ws; (void)ws_size;
}